// Round 1
// baseline (1021.592 us; speedup 1.0000x reference)
//
#include <hip/hip_runtime.h>

#define NNODES 50000
#define CIN    128
#define COUT   256
#define KTOT   256   // 2*CIN

// ---------------------------------------------------------------------------
// Kernel 0: fill m with -inf (ws is poisoned 0xAA before every launch)
// ---------------------------------------------------------------------------
__global__ void fill_neg_inf(float4* __restrict__ m, int n4) {
    int i = blockIdx.x * blockDim.x + threadIdx.x;
    int stride = gridDim.x * blockDim.x;
    const float NI = __int_as_float(0xFF800000);
    float4 v = make_float4(NI, NI, NI, NI);
    for (int j = i; j < n4; j += stride) m[j] = v;
}

// ---------------------------------------------------------------------------
// Kernel 1: scatter-max of x[src] rows into m[dst] rows.
// One 64-lane wave per edge; each lane handles 2 channels (float2 = 8B/lane,
// 512B contiguous per row read -> fully coalesced).
// Float atomic max via signed-int max (>=0) / unsigned-int min (<0) trick.
// ---------------------------------------------------------------------------
__device__ __forceinline__ void atomicMaxF(float* addr, float v) {
    if (v >= 0.0f) atomicMax((int*)addr, __float_as_int(v));
    else           atomicMin((unsigned int*)addr, __float_as_uint(v));
}

__global__ void scatter_max_kernel(const float* __restrict__ x,
                                   const int* __restrict__ src,
                                   const int* __restrict__ dst,
                                   float* __restrict__ m, int E) {
    int gtid = blockIdx.x * blockDim.x + threadIdx.x;
    int e    = gtid >> 6;
    if (e >= E) return;
    int lane = threadIdx.x & 63;
    int s = src[e];
    int d = dst[e];
    const float2 v = ((const float2*)(x + (size_t)s * CIN))[lane];
    float* mr = m + (size_t)d * CIN + lane * 2;
    atomicMaxF(mr + 0, v.x);
    atomicMaxF(mr + 1, v.y);
}

// ---------------------------------------------------------------------------
// Kernel 2: fused  out = relu( [x | (m - x, empty->0)] @ W^T + b )
// Tile: 64 rows x 256 cols per block, BK=32, 256 threads.
// Each thread: 4 rows x 16 cols register tile.
// LDS: As[32][64] (k-major) 8KB + Bs[32][256] 32KB = 40KB -> 4 blocks/CU.
// ---------------------------------------------------------------------------
__global__ __launch_bounds__(256, 4)
void fused_gemm(const float* __restrict__ x,
                const float* __restrict__ m,
                const float* __restrict__ W,
                const float* __restrict__ bias,
                float* __restrict__ out) {
    __shared__ float As[32][64];
    __shared__ float Bs[32][256];

    const int tid  = threadIdx.x;
    const int row0 = blockIdx.x * 64;
    const int tr   = tid >> 4;   // 0..15
    const int tc   = tid & 15;   // 0..15

    float acc[4][16];
#pragma unroll
    for (int i = 0; i < 4; ++i)
#pragma unroll
        for (int j = 0; j < 16; ++j) acc[i][j] = 0.0f;

    const int  ar     = tid >> 2;        // 0..63 row within tile
    const int  aseg   = (tid & 3) * 8;   // col offset within K-chunk
    const int  grow   = row0 + ar;
    const bool rvalid = (grow < NNODES);

    for (int kk = 0; kk < KTOT; kk += 32) {
        // ---- stage A tile (concat + xj computed on the fly) ----
        float av[8];
        if (!rvalid) {
#pragma unroll
            for (int j = 0; j < 8; ++j) av[j] = 0.0f;
        } else if (kk < CIN) {
            const float4* p = (const float4*)(x + (size_t)grow * CIN + kk + aseg);
            float4 a0 = p[0], a1 = p[1];
            av[0] = a0.x; av[1] = a0.y; av[2] = a0.z; av[3] = a0.w;
            av[4] = a1.x; av[5] = a1.y; av[6] = a1.z; av[7] = a1.w;
        } else {
            int cc = kk - CIN + aseg;
            const float4* pm = (const float4*)(m + (size_t)grow * CIN + cc);
            const float4* px = (const float4*)(x + (size_t)grow * CIN + cc);
            float4 m0 = pm[0], m1 = pm[1];
            float4 x0 = px[0], x1 = px[1];
            av[0] = (__float_as_uint(m0.x) == 0xFF800000u) ? 0.0f : m0.x - x0.x;
            av[1] = (__float_as_uint(m0.y) == 0xFF800000u) ? 0.0f : m0.y - x0.y;
            av[2] = (__float_as_uint(m0.z) == 0xFF800000u) ? 0.0f : m0.z - x0.z;
            av[3] = (__float_as_uint(m0.w) == 0xFF800000u) ? 0.0f : m0.w - x0.w;
            av[4] = (__float_as_uint(m1.x) == 0xFF800000u) ? 0.0f : m1.x - x1.x;
            av[5] = (__float_as_uint(m1.y) == 0xFF800000u) ? 0.0f : m1.y - x1.y;
            av[6] = (__float_as_uint(m1.z) == 0xFF800000u) ? 0.0f : m1.z - x1.z;
            av[7] = (__float_as_uint(m1.w) == 0xFF800000u) ? 0.0f : m1.w - x1.w;
        }
#pragma unroll
        for (int j = 0; j < 8; ++j) As[aseg + j][ar] = av[j];

        // ---- stage B tile: W[o][kk..kk+31] transposed into Bs[k][o] ----
        {
            const float4* p = (const float4*)(W + (size_t)tid * KTOT + kk);
#pragma unroll
            for (int s = 0; s < 8; ++s) {
                float4 w = p[s];
                Bs[s * 4 + 0][tid] = w.x;
                Bs[s * 4 + 1][tid] = w.y;
                Bs[s * 4 + 2][tid] = w.z;
                Bs[s * 4 + 3][tid] = w.w;
            }
        }
        __syncthreads();

        // ---- inner product ----
#pragma unroll
        for (int k = 0; k < 32; ++k) {
            float4 a = *(const float4*)&As[k][tr * 4];
            float a4[4] = {a.x, a.y, a.z, a.w};
#pragma unroll
            for (int q = 0; q < 4; ++q) {
                float4 b4 = *(const float4*)&Bs[k][tc * 16 + q * 4];
                float bv[4] = {b4.x, b4.y, b4.z, b4.w};
#pragma unroll
                for (int i = 0; i < 4; ++i)
#pragma unroll
                    for (int j = 0; j < 4; ++j)
                        acc[i][q * 4 + j] = fmaf(a4[i], bv[j], acc[i][q * 4 + j]);
            }
        }
        __syncthreads();
    }

    // ---- epilogue: bias + relu + store ----
#pragma unroll
    for (int q = 0; q < 4; ++q) {
        int col = tc * 16 + q * 4;
        float4 bv = *(const float4*)&bias[col];
#pragma unroll
        for (int i = 0; i < 4; ++i) {
            int r = row0 + tr * 4 + i;
            if (r < NNODES) {
                float4 o;
                o.x = fmaxf(acc[i][q * 4 + 0] + bv.x, 0.0f);
                o.y = fmaxf(acc[i][q * 4 + 1] + bv.y, 0.0f);
                o.z = fmaxf(acc[i][q * 4 + 2] + bv.z, 0.0f);
                o.w = fmaxf(acc[i][q * 4 + 3] + bv.w, 0.0f);
                *(float4*)(out + (size_t)r * COUT + col) = o;
            }
        }
    }
}

// ---------------------------------------------------------------------------
extern "C" void kernel_launch(void* const* d_in, const int* in_sizes, int n_in,
                              void* d_out, int out_size, void* d_ws, size_t ws_size,
                              hipStream_t stream) {
    const float* x  = (const float*)d_in[0];
    const int*   ei = (const int*)d_in[1];
    const float* W  = (const float*)d_in[2];
    const float* b  = (const float*)d_in[3];
    float*       out = (float*)d_out;
    float*       m   = (float*)d_ws;   // [NNODES][CIN] scatter-max workspace

    const int E = in_sizes[1] / 2;
    const int* src = ei;
    const int* dst = ei + E;

    // 1) init m = -inf
    int n4 = NNODES * CIN / 4;
    fill_neg_inf<<<2048, 256, 0, stream>>>((float4*)m, n4);

    // 2) scatter-max x[src] rows into m[dst] rows (1 wave per edge)
    int nthreads = E * 64;
    int nblocks  = (nthreads + 255) / 256;
    scatter_max_kernel<<<nblocks, 256, 0, stream>>>(x, src, dst, m, E);

    // 3) fused concat + GEMM + bias + relu
    int gblocks = (NNODES + 63) / 64;
    fused_gemm<<<gblocks, 256, 0, stream>>>(x, m, W, b, out);
}

// Round 2
// 347.503 us; speedup vs baseline: 2.9398x; 2.9398x over previous
//
#include <hip/hip_runtime.h>

#define NNODES 50000
#define CIN    128
#define COUT   256
#define KTOT   256   // 2*CIN

// ---------------------------------------------------------------------------
// ws layout (all 4-byte elems):
//   xj         float[NNODES*CIN]   = 6,400,000
//   cnt        int[NNODES]         =    50,000
//   row_start  int[NNODES+1]       =    50,001
//   sorted_src int[E]              =   600,000
// total ~28.4 MB
// ---------------------------------------------------------------------------

__global__ void zero_cnt(int* __restrict__ cnt, int n) {
    int i = blockIdx.x * blockDim.x + threadIdx.x;
    if (i < n) cnt[i] = 0;
}

__global__ void hist_kernel(const int* __restrict__ dst, int* __restrict__ cnt, int E) {
    int i = blockIdx.x * blockDim.x + threadIdx.x;
    if (i < E) atomicAdd(&cnt[dst[i]], 1);
}

// block-level partial sums of cnt (256 elems per block)
__global__ void scan_partial(const int* __restrict__ cnt, int* __restrict__ partial, int n) {
    __shared__ int s[256];
    int tid = threadIdx.x;
    int i = blockIdx.x * 256 + tid;
    s[tid] = (i < n) ? cnt[i] : 0;
    __syncthreads();
    for (int off = 128; off > 0; off >>= 1) {
        if (tid < off) s[tid] += s[tid + off];
        __syncthreads();
    }
    if (tid == 0) partial[blockIdx.x] = s[0];
}

// exclusive scan of the per-block partials (np <= 256), single block
__global__ void scan_root(int* __restrict__ partial, int np) {
    __shared__ int s[256];
    int tid = threadIdx.x;
    int v = (tid < np) ? partial[tid] : 0;
    s[tid] = v;
    __syncthreads();
    for (int off = 1; off < 256; off <<= 1) {
        int t = (tid >= off) ? s[tid - off] : 0;
        __syncthreads();
        s[tid] += t;
        __syncthreads();
    }
    if (tid < np) partial[tid] = s[tid] - v;   // exclusive
}

// per-block inclusive scan + partial offset -> exclusive row_start
__global__ void scan_final(const int* __restrict__ cnt, const int* __restrict__ partial,
                           int* __restrict__ row_start, int n) {
    __shared__ int s[256];
    int tid = threadIdx.x;
    int i = blockIdx.x * 256 + tid;
    int v = (i < n) ? cnt[i] : 0;
    s[tid] = v;
    __syncthreads();
    for (int off = 1; off < 256; off <<= 1) {
        int t = (tid >= off) ? s[tid - off] : 0;
        __syncthreads();
        s[tid] += t;
        __syncthreads();
    }
    int incl = s[tid];
    int base = partial[blockIdx.x];
    if (i < n) row_start[i] = base + incl - v;
    if (i == n - 1) row_start[n] = base + incl;   // total
}

// rank-scatter: consumes cnt down to zero (no re-zero needed)
__global__ void scatter_kernel(const int* __restrict__ src, const int* __restrict__ dst,
                               const int* __restrict__ row_start, int* __restrict__ cnt,
                               int* __restrict__ sorted_src, int E) {
    int i = blockIdx.x * blockDim.x + threadIdx.x;
    if (i < E) {
        int d = dst[i];
        int pos = atomicSub(&cnt[d], 1) - 1;        // 0..deg-1
        sorted_src[row_start[d] + pos] = src[i];
    }
}

// ---------------------------------------------------------------------------
// gather-max: one wave per node; lane handles 2 channels (float2).
// xj[n] = (deg>0) ? max_over_src(x[src]) - x[n] : 0
// ---------------------------------------------------------------------------
__global__ __launch_bounds__(256)
void gather_max_kernel(const float* __restrict__ x,
                       const int* __restrict__ row_start,
                       const int* __restrict__ sorted_src,
                       float* __restrict__ xj) {
    int wid  = (blockIdx.x * blockDim.x + threadIdx.x) >> 6;  // node id
    int lane = threadIdx.x & 63;
    if (wid >= NNODES) return;

    int start = row_start[wid];
    int end   = row_start[wid + 1];

    const float NI = __int_as_float(0xFF800000);
    float2 mx = make_float2(NI, NI);

    for (int base = start; base < end; base += 64) {
        int li = base + lane;
        int si = (li < end) ? sorted_src[li] : 0;
        int c  = min(64, end - base);
        for (int t = 0; t < c; ++t) {
            int s = __shfl(si, t);
            float2 v = ((const float2*)(x + (size_t)s * CIN))[lane];
            mx.x = fmaxf(mx.x, v.x);
            mx.y = fmaxf(mx.y, v.y);
        }
    }

    float2 xv = ((const float2*)(x + (size_t)wid * CIN))[lane];
    float2 o;
    bool nonempty = (end > start);
    o.x = nonempty ? mx.x - xv.x : 0.0f;
    o.y = nonempty ? mx.y - xv.y : 0.0f;
    ((float2*)(xj + (size_t)wid * CIN))[lane] = o;
}

// ---------------------------------------------------------------------------
// fused  out = relu( [x | xj] @ W^T + b )
// Tile: 64 rows x 256 cols per block, BK=32, 256 threads, 4x16 reg tile.
// ---------------------------------------------------------------------------
__global__ __launch_bounds__(256, 4)
void fused_gemm(const float* __restrict__ x,
                const float* __restrict__ xj,
                const float* __restrict__ W,
                const float* __restrict__ bias,
                float* __restrict__ out) {
    __shared__ float As[32][64];
    __shared__ float Bs[32][256];

    const int tid  = threadIdx.x;
    const int row0 = blockIdx.x * 64;
    const int tr   = tid >> 4;   // 0..15
    const int tc   = tid & 15;   // 0..15

    float acc[4][16];
#pragma unroll
    for (int i = 0; i < 4; ++i)
#pragma unroll
        for (int j = 0; j < 16; ++j) acc[i][j] = 0.0f;

    const int  ar     = tid >> 2;        // 0..63 row within tile
    const int  aseg   = (tid & 3) * 8;   // col offset within K-chunk
    const int  grow   = row0 + ar;
    const bool rvalid = (grow < NNODES);

    for (int kk = 0; kk < KTOT; kk += 32) {
        // ---- stage A tile (concat on the fly) ----
        float av[8];
        if (!rvalid) {
#pragma unroll
            for (int j = 0; j < 8; ++j) av[j] = 0.0f;
        } else {
            const float* srcp = (kk < CIN) ? (x + (size_t)grow * CIN + kk + aseg)
                                           : (xj + (size_t)grow * CIN + (kk - CIN) + aseg);
            const float4* p = (const float4*)srcp;
            float4 a0 = p[0], a1 = p[1];
            av[0] = a0.x; av[1] = a0.y; av[2] = a0.z; av[3] = a0.w;
            av[4] = a1.x; av[5] = a1.y; av[6] = a1.z; av[7] = a1.w;
        }
#pragma unroll
        for (int j = 0; j < 8; ++j) As[aseg + j][ar] = av[j];

        // ---- stage B tile: W[o][kk..kk+31] transposed into Bs[k][o] ----
        {
            const float4* p = (const float4*)(W + (size_t)tid * KTOT + kk);
#pragma unroll
            for (int s = 0; s < 8; ++s) {
                float4 w = p[s];
                Bs[s * 4 + 0][tid] = w.x;
                Bs[s * 4 + 1][tid] = w.y;
                Bs[s * 4 + 2][tid] = w.z;
                Bs[s * 4 + 3][tid] = w.w;
            }
        }
        __syncthreads();

        // ---- inner product ----
#pragma unroll
        for (int k = 0; k < 32; ++k) {
            float4 a = *(const float4*)&As[k][tr * 4];
            float a4[4] = {a.x, a.y, a.z, a.w};
#pragma unroll
            for (int q = 0; q < 4; ++q) {
                float4 b4 = *(const float4*)&Bs[k][tc * 16 + q * 4];
                float bv[4] = {b4.x, b4.y, b4.z, b4.w};
#pragma unroll
                for (int i = 0; i < 4; ++i)
#pragma unroll
                    for (int j = 0; j < 4; ++j)
                        acc[i][q * 4 + j] = fmaf(a4[i], bv[j], acc[i][q * 4 + j]);
            }
        }
        __syncthreads();
    }

    // ---- epilogue: bias + relu + store ----
#pragma unroll
    for (int q = 0; q < 4; ++q) {
        int col = tc * 16 + q * 4;
        float4 bv = *(const float4*)&bias[col];
#pragma unroll
        for (int i = 0; i < 4; ++i) {
            int r = row0 + tr * 4 + i;
            if (r < NNODES) {
                float4 o;
                o.x = fmaxf(acc[i][q * 4 + 0] + bv.x, 0.0f);
                o.y = fmaxf(acc[i][q * 4 + 1] + bv.y, 0.0f);
                o.z = fmaxf(acc[i][q * 4 + 2] + bv.z, 0.0f);
                o.w = fmaxf(acc[i][q * 4 + 3] + bv.w, 0.0f);
                *(float4*)(out + (size_t)r * COUT + col) = o;
            }
        }
    }
}

// ---------------------------------------------------------------------------
extern "C" void kernel_launch(void* const* d_in, const int* in_sizes, int n_in,
                              void* d_out, int out_size, void* d_ws, size_t ws_size,
                              hipStream_t stream) {
    const float* x  = (const float*)d_in[0];
    const int*   ei = (const int*)d_in[1];
    const float* W  = (const float*)d_in[2];
    const float* b  = (const float*)d_in[3];
    float*       out = (float*)d_out;

    const int E = in_sizes[1] / 2;
    const int* src = ei;
    const int* dst = ei + E;

    // ws carve-up
    float* xj         = (float*)d_ws;
    int*   cnt        = (int*)(xj + (size_t)NNODES * CIN);
    int*   row_start  = cnt + NNODES;
    int*   sorted_src = row_start + (NNODES + 1);

    const int NB_N = (NNODES + 255) / 256;   // 196
    const int NB_E = (E + 255) / 256;

    zero_cnt<<<NB_N, 256, 0, stream>>>(cnt, NNODES);
    hist_kernel<<<NB_E, 256, 0, stream>>>(dst, cnt, E);

    // exclusive scan of cnt -> row_start (reuses sorted_src[0..NB_N) as partial buf? no:
    // partials stored in row_start tail is unsafe; use a dedicated slice after sorted_src)
    int* partial = sorted_src + E;           // 196 ints scratch
    scan_partial<<<NB_N, 256, 0, stream>>>(cnt, partial, NNODES);
    scan_root<<<1, 256, 0, stream>>>(partial, NB_N);
    scan_final<<<NB_N, 256, 0, stream>>>(cnt, partial, row_start, NNODES);

    scatter_kernel<<<NB_E, 256, 0, stream>>>(src, dst, row_start, cnt, sorted_src, E);

    gather_max_kernel<<<(NNODES * 64 + 255) / 256, 256, 0, stream>>>(x, row_start, sorted_src, xj);

    fused_gemm<<<(NNODES + 63) / 64, 256, 0, stream>>>(x, xj, W, b, out);
}

// Round 3
// 218.025 us; speedup vs baseline: 4.6857x; 1.5939x over previous
//
#include <hip/hip_runtime.h>

#define NNODES 50000
#define CIN    128
#define COUT   256
#define KTOT   256   // 2*CIN

typedef float  f32x4  __attribute__((ext_vector_type(4)));
typedef short  bf16x8 __attribute__((ext_vector_type(8)));

#define GLOAD16(gptr, lptr) __builtin_amdgcn_global_load_lds(                      \
    (const __attribute__((address_space(1))) void*)(gptr),                         \
    (__attribute__((address_space(3))) void*)(lptr), 16, 0, 0)

__device__ __forceinline__ unsigned short f2bf(float f) {
    union { float f; unsigned int u; } v; v.f = f;
    unsigned int r = v.u + 0x7FFFu + ((v.u >> 16) & 1u);   // RNE
    return (unsigned short)(r >> 16);
}

// ---------------------------------------------------------------------------
// CSR build
// ---------------------------------------------------------------------------
__global__ void zero_cnt(int* __restrict__ cnt, int n) {
    int i = blockIdx.x * blockDim.x + threadIdx.x;
    if (i < n) cnt[i] = 0;
}

__global__ void hist_kernel(const int* __restrict__ dst, int* __restrict__ cnt, int E) {
    int i = blockIdx.x * blockDim.x + threadIdx.x;
    if (i < E) atomicAdd(&cnt[dst[i]], 1);
}

__global__ void scan_partial(const int* __restrict__ cnt, int* __restrict__ partial, int n) {
    __shared__ int s[256];
    int tid = threadIdx.x;
    int i = blockIdx.x * 256 + tid;
    s[tid] = (i < n) ? cnt[i] : 0;
    __syncthreads();
    for (int off = 128; off > 0; off >>= 1) {
        if (tid < off) s[tid] += s[tid + off];
        __syncthreads();
    }
    if (tid == 0) partial[blockIdx.x] = s[0];
}

__global__ void scan_root(int* __restrict__ partial, int np) {
    __shared__ int s[256];
    int tid = threadIdx.x;
    int v = (tid < np) ? partial[tid] : 0;
    s[tid] = v;
    __syncthreads();
    for (int off = 1; off < 256; off <<= 1) {
        int t = (tid >= off) ? s[tid - off] : 0;
        __syncthreads();
        s[tid] += t;
        __syncthreads();
    }
    if (tid < np) partial[tid] = s[tid] - v;   // exclusive
}

__global__ void scan_final(const int* __restrict__ cnt, const int* __restrict__ partial,
                           int* __restrict__ row_start, int n) {
    __shared__ int s[256];
    int tid = threadIdx.x;
    int i = blockIdx.x * 256 + tid;
    int v = (i < n) ? cnt[i] : 0;
    s[tid] = v;
    __syncthreads();
    for (int off = 1; off < 256; off <<= 1) {
        int t = (tid >= off) ? s[tid - off] : 0;
        __syncthreads();
        s[tid] += t;
        __syncthreads();
    }
    int incl = s[tid];
    int base = partial[blockIdx.x];
    if (i < n) row_start[i] = base + incl - v;
    if (i == n - 1) row_start[n] = base + incl;
}

__global__ void scatter_kernel(const int* __restrict__ src, const int* __restrict__ dst,
                               const int* __restrict__ row_start, int* __restrict__ cnt,
                               int* __restrict__ sorted_src, int E) {
    int i = blockIdx.x * blockDim.x + threadIdx.x;
    if (i < E) {
        int d = dst[i];
        int pos = atomicSub(&cnt[d], 1) - 1;
        sorted_src[row_start[d] + pos] = src[i];
    }
}

// ---------------------------------------------------------------------------
// gather-max + bf16 concat emit: xcat[n] = [bf16(x[n]) | bf16(max - x[n])]
// one wave per node, lane = 2 channels (float2), 4-way edge ILP
// ---------------------------------------------------------------------------
__device__ __forceinline__ float2 fmax2(float2 a, float2 b) {
    return make_float2(fmaxf(a.x, b.x), fmaxf(a.y, b.y));
}

__global__ __launch_bounds__(256)
void gather_max_kernel(const float* __restrict__ x,
                       const int* __restrict__ row_start,
                       const int* __restrict__ sorted_src,
                       unsigned short* __restrict__ xcat) {
    int wid  = (blockIdx.x * blockDim.x + threadIdx.x) >> 6;
    int lane = threadIdx.x & 63;
    if (wid >= NNODES) return;

    int start = row_start[wid];
    int end   = row_start[wid + 1];

    const float NI = __int_as_float(0xFF800000u);
    float2 m0 = make_float2(NI, NI), m1 = m0, m2 = m0, m3 = m0;

    int t = start;
    for (; t + 4 <= end; t += 4) {
        int s0 = sorted_src[t + 0];
        int s1 = sorted_src[t + 1];
        int s2 = sorted_src[t + 2];
        int s3 = sorted_src[t + 3];
        float2 v0 = ((const float2*)(x + (size_t)s0 * CIN))[lane];
        float2 v1 = ((const float2*)(x + (size_t)s1 * CIN))[lane];
        float2 v2 = ((const float2*)(x + (size_t)s2 * CIN))[lane];
        float2 v3 = ((const float2*)(x + (size_t)s3 * CIN))[lane];
        m0 = fmax2(m0, v0); m1 = fmax2(m1, v1);
        m2 = fmax2(m2, v2); m3 = fmax2(m3, v3);
    }
    for (; t < end; ++t) {
        int s = sorted_src[t];
        m0 = fmax2(m0, ((const float2*)(x + (size_t)s * CIN))[lane]);
    }
    float2 mx = fmax2(fmax2(m0, m1), fmax2(m2, m3));

    float2 xv = ((const float2*)(x + (size_t)wid * CIN))[lane];
    bool nonempty = (end > start);
    float2 o;
    o.x = nonempty ? mx.x - xv.x : 0.0f;
    o.y = nonempty ? mx.y - xv.y : 0.0f;

    ushort2 px = make_ushort2(f2bf(xv.x), f2bf(xv.y));
    ushort2 pj = make_ushort2(f2bf(o.x),  f2bf(o.y));
    *((ushort2*)(xcat + (size_t)wid * KTOT + lane * 2))        = px;
    *((ushort2*)(xcat + (size_t)wid * KTOT + CIN + lane * 2))  = pj;
}

// ---------------------------------------------------------------------------
// W (f32 [COUT][KTOT], row-major, k contiguous) -> bf16, same layout.
// ---------------------------------------------------------------------------
__global__ void convert_w(const float* __restrict__ W, unsigned short* __restrict__ Wbf) {
    int i = blockIdx.x * blockDim.x + threadIdx.x;   // 16384 threads, 4 elems each
    float4 v = ((const float4*)W)[i];
    ushort4 p = make_ushort4(f2bf(v.x), f2bf(v.y), f2bf(v.z), f2bf(v.w));
    *((ushort4*)(Wbf + (size_t)i * 4)) = p;
}

// ---------------------------------------------------------------------------
// MFMA GEMM: out = relu( xcat[M][256](bf16) @ Wbf[N][256](bf16)^T + bias )
// 128x128 tile, 4 waves (2x2), 16x16x32 bf16 MFMA, BK=32, double-buffered LDS,
// global_load_lds width 16.
// ---------------------------------------------------------------------------
__global__ __launch_bounds__(256, 3)
void mfma_gemm(const unsigned short* __restrict__ xcat,
               const unsigned short* __restrict__ Wbf,
               const float* __restrict__ bias,
               float* __restrict__ out) {
    __shared__ unsigned short As[2][128][32];   // 16 KB
    __shared__ unsigned short Bs[2][128][32];   // 16 KB (n-major, k contiguous)

    const int M = NNODES;
    const int bx = blockIdx.x;
    const int nb = bx & 1;          // 2 N-blocks
    const int mb = bx >> 1;         // 391 M-blocks
    const int m0 = mb * 128, n0 = nb * 128;

    const int tid  = threadIdx.x;
    const int lane = tid & 63;
    const int wid  = tid >> 6;
    const int wm   = wid >> 1;      // 0..1
    const int wn   = wid & 1;       // 0..1

    f32x4 acc[4][4] = {};

    // stage K-slice kt into buffer b (A: rows m0.., B: rows n0..)
    auto stage = [&](int b, int kt) {
#pragma unroll
        for (int j = 0; j < 2; ++j) {
            int u    = j * 256 + tid;       // 0..511
            int row  = u >> 2;
            int kseg = (u & 3) * 8;
            int grow = m0 + row; if (grow > M - 1) grow = M - 1;
            GLOAD16(xcat + (size_t)grow * KTOT + kt + kseg, &As[b][row][kseg]);
            GLOAD16(Wbf  + (size_t)(n0 + row) * KTOT + kt + kseg, &Bs[b][row][kseg]);
        }
    };

    stage(0, 0);
    __syncthreads();

    const int l15 = lane & 15;
    const int kh  = (lane >> 4) * 8;

#pragma unroll
    for (int t = 0; t < 8; ++t) {
        int b = t & 1;
        if (t < 7) stage(b ^ 1, (t + 1) * 32);

        bf16x8 af[4], bfr[4];
#pragma unroll
        for (int m = 0; m < 4; ++m)
            af[m] = *(const bf16x8*)&As[b][wm * 64 + m * 16 + l15][kh];
#pragma unroll
        for (int n = 0; n < 4; ++n)
            bfr[n] = *(const bf16x8*)&Bs[b][wn * 64 + n * 16 + l15][kh];
#pragma unroll
        for (int m = 0; m < 4; ++m)
#pragma unroll
            for (int n = 0; n < 4; ++n)
                acc[m][n] = __builtin_amdgcn_mfma_f32_16x16x32_bf16(af[m], bfr[n], acc[m][n], 0, 0, 0);

        __syncthreads();   // drains vmcnt -> next buffer ready; protects buffer reuse
    }

    // epilogue: bias + relu; C/D layout col=lane&15, row=(lane>>4)*4+reg
#pragma unroll
    for (int n = 0; n < 4; ++n) {
        int col = n0 + wn * 64 + n * 16 + l15;
        float bv = bias[col];
#pragma unroll
        for (int m = 0; m < 4; ++m) {
            int r0 = m0 + wm * 64 + m * 16 + ((lane >> 4) << 2);
            f32x4 a = acc[m][n];
#pragma unroll
            for (int r = 0; r < 4; ++r) {
                int rr = r0 + r;
                if (rr < M) out[(size_t)rr * COUT + col] = fmaxf(a[r] + bv, 0.0f);
            }
        }
    }
}

// ---------------------------------------------------------------------------
extern "C" void kernel_launch(void* const* d_in, const int* in_sizes, int n_in,
                              void* d_out, int out_size, void* d_ws, size_t ws_size,
                              hipStream_t stream) {
    const float* x  = (const float*)d_in[0];
    const int*   ei = (const int*)d_in[1];
    const float* W  = (const float*)d_in[2];
    const float* b  = (const float*)d_in[3];
    float*       out = (float*)d_out;

    const int E = in_sizes[1] / 2;
    const int* src = ei;
    const int* dst = ei + E;

    // ws carve-up (4B units): xcat bf16 [50000][256] -> 12.8 MB
    unsigned short* xcat      = (unsigned short*)d_ws;
    unsigned short* Wbf       = xcat + (size_t)NNODES * KTOT;      // 128 KB
    int*            cnt       = (int*)(Wbf + COUT * KTOT);
    int*            row_start = cnt + NNODES;
    int*            sorted_src= row_start + (NNODES + 1);
    int*            partial   = sorted_src + E;                    // 196 ints

    const int NB_N = (NNODES + 255) / 256;   // 196
    const int NB_E = (E + 255) / 256;

    convert_w<<<64, 256, 0, stream>>>(W, Wbf);
    zero_cnt<<<NB_N, 256, 0, stream>>>(cnt, NNODES);
    hist_kernel<<<NB_E, 256, 0, stream>>>(dst, cnt, E);
    scan_partial<<<NB_N, 256, 0, stream>>>(cnt, partial, NNODES);
    scan_root<<<1, 256, 0, stream>>>(partial, NB_N);
    scan_final<<<NB_N, 256, 0, stream>>>(cnt, partial, row_start, NNODES);
    scatter_kernel<<<NB_E, 256, 0, stream>>>(src, dst, row_start, cnt, sorted_src, E);
    gather_max_kernel<<<(NNODES * 64 + 255) / 256, 256, 0, stream>>>(x, row_start, sorted_src, xcat);
    mfma_gemm<<<((NNODES + 127) / 128) * 2, 256, 0, stream>>>(xcat, Wbf, b, out);
}